// Round 1
// baseline (1287.142 us; speedup 1.0000x reference)
//
#include <hip/hip_runtime.h>
#include <hip/hip_bf16.h>

typedef unsigned int u32;
typedef unsigned short u16;

#define TOK   2048   // B*N
#define DIM   1024   // D
#define NH    8
#define KDD   128
#define NKEY  256
#define NTOPK 16
#define QC    2048   // q columns = 2*NH*KDD

// ---- workspace layout (float offsets) ----
#define WS_SCALE  64ull
#define WS_SHIFT  (WS_SCALE + DIM)
#define WS_PS     (WS_SHIFT + DIM)            // 16*1024 partial sums
#define WS_PSS    (WS_PS + 16ull*DIM)         // 16*1024 partial sumsq
#define WS_Q      35072ull                    // 2048*2048
#define WS_SIM    (WS_Q + (size_t)TOK*QC)     // 2*2048*8*256
#define WS_S1S    (WS_SIM + 2ull*TOK*NH*NKEY) // stage1 scores [2][T][H][16]
#define WS_S1I    (WS_S1S + 2ull*TOK*NH*NTOPK)
#define WS_GATE   (WS_S1I + 2ull*TOK*NH*NTOPK)// [T][H][16] sigmoid(score)
#define WS_EIDX   (WS_GATE + (size_t)TOK*NH*NTOPK)
// total ~14.2M floats = ~57 MB of d_ws

__device__ __forceinline__ float bf2f(u16 u){ return __uint_as_float(((u32)u)<<16); }
__device__ __forceinline__ u16 f2bf(float f){ u32 x=__float_as_uint(f); return (u16)((x + 0x7fffu + ((x>>16)&1u))>>16); }

__device__ __forceinline__ float LD1(const float* p, size_t i){ return p[i]; }
__device__ __forceinline__ float LD1(const u16* p, size_t i){ return bf2f(p[i]); }
__device__ __forceinline__ float2 LD2(const float* p, size_t i){ return *reinterpret_cast<const float2*>(p+i); }
__device__ __forceinline__ float2 LD2(const u16* p, size_t i){
  u32 w = *reinterpret_cast<const u32*>(p+i);
  return make_float2(bf2f((u16)(w & 0xffffu)), bf2f((u16)(w >> 16)));
}
__device__ __forceinline__ void ST2(float* p, size_t i, float a, float b){ *reinterpret_cast<float2*>(p+i) = make_float2(a,b); }
__device__ __forceinline__ void ST2(u16* p, size_t i, float a, float b){
  u32 w = (u32)f2bf(a) | ((u32)f2bf(b) << 16);
  *reinterpret_cast<u32*>(p+i) = w;
}

// ---- dtype detection: bn_gamma is all ones. fp32 1.0 = 0x3F800000; two bf16 1.0 = 0x3F803F80
__global__ void k_detect(const u32* gamma_bits, int* flag){
  if (threadIdx.x == 0) *flag = (gamma_bits[0] == 0x3F800000u) ? 0 : 1;
}

// ---- BN stage 1: partial sums over 128-token chunks, per feature ----
template<typename T>
__device__ void bn_part_body(const T* x, float* ps, float* pss){
  int tid = threadIdx.x;
  int fc = blockIdx.x & 3, tc = blockIdx.x >> 2;
  int f = fc*256 + tid;
  float s = 0.f, ss = 0.f;
  int t0 = tc*128;
  for (int i = 0; i < 128; ++i){
    float v = LD1(x, (size_t)(t0+i)*DIM + f);
    s += v; ss += v*v;
  }
  ps[(size_t)tc*DIM + f] = s;
  pss[(size_t)tc*DIM + f] = ss;
}
__global__ __launch_bounds__(256) void k_bn_part(const void* x, const int* flag, float* ws){
  float* ps = ws + WS_PS; float* pss = ws + WS_PSS;
  if (*flag) bn_part_body((const u16*)x, ps, pss);
  else       bn_part_body((const float*)x, ps, pss);
}

// ---- BN stage 2: finalize scale/shift: xn = x*scale + shift ----
template<typename T>
__device__ void bn_final_body(const T* gamma, const T* beta, float* ws){
  int f = blockIdx.x*256 + threadIdx.x;
  float s = 0.f, ss = 0.f;
  for (int c = 0; c < 16; ++c){ s += ws[WS_PS + (size_t)c*DIM + f]; ss += ws[WS_PSS + (size_t)c*DIM + f]; }
  float mean = s * (1.0f/TOK);
  float var  = ss * (1.0f/TOK) - mean*mean;
  float rs = (float)(1.0 / sqrt((double)var + 1e-5));
  float g = LD1(gamma, (size_t)f), b = LD1(beta, (size_t)f);
  ws[WS_SCALE + f] = g*rs;
  ws[WS_SHIFT + f] = b - mean*g*rs;
}
__global__ __launch_bounds__(256) void k_bn_final(const void* gamma, const void* beta, const int* flag, float* ws){
  if (*flag) bn_final_body((const u16*)gamma, (const u16*)beta, ws);
  else       bn_final_body((const float*)gamma, (const float*)beta, ws);
}

// ---- q = xn @ Wq : fp32 tiled GEMM, 128x128 block tile, 8x8 microtile ----
template<typename T>
__device__ void qgemm_body(const T* x, const T* wq, float* ws, float (*At)[17], float (*Bt)[129]){
  float* qm = ws + WS_Q;
  const float* scale = ws + WS_SCALE;
  const float* shift = ws + WS_SHIFT;
  int tid = threadIdx.x;
  int tx = tid & 15, ty = tid >> 4;
  int bm = blockIdx.x, bn = blockIdx.y;
  float acc[8][8] = {};
  for (int k0 = 0; k0 < DIM; k0 += 16){
    __syncthreads();
    { // stage A (xn on the fly): 128 rows x 16 k
      int m = tid >> 1, kb = (tid & 1)*8;
      size_t base = (size_t)(bm*128 + m)*DIM + k0 + kb;
      #pragma unroll
      for (int i = 0; i < 8; ++i){
        int d = k0 + kb + i;
        At[m][kb+i] = LD1(x, base + i)*scale[d] + shift[d];
      }
    }
    { // stage B: 16 k x 128 cols
      int kk = tid >> 4, nb = (tid & 15)*8;
      size_t base = (size_t)(k0 + kk)*QC + bn*128 + nb;
      #pragma unroll
      for (int j = 0; j < 8; ++j) Bt[kk][nb+j] = LD1(wq, base + j);
    }
    __syncthreads();
    #pragma unroll 4
    for (int kk = 0; kk < 16; ++kk){
      float a[8], b[8];
      #pragma unroll
      for (int i = 0; i < 8; ++i) a[i] = At[ty*8+i][kk];
      #pragma unroll
      for (int j = 0; j < 8; ++j) b[j] = Bt[kk][tx*8+j];
      #pragma unroll
      for (int i = 0; i < 8; ++i)
        #pragma unroll
        for (int j = 0; j < 8; ++j) acc[i][j] += a[i]*b[j];
    }
  }
  for (int i = 0; i < 8; ++i){
    size_t row = (size_t)(bm*128 + ty*8 + i)*QC + bn*128 + tx*8;
    #pragma unroll
    for (int j = 0; j < 8; ++j) qm[row + j] = acc[i][j];
  }
}
__global__ __launch_bounds__(256) void k_qgemm(const void* x, const void* wq, const int* flag, float* ws){
  __shared__ float At[128][17];
  __shared__ float Bt[16][129];
  if (*flag) qgemm_body((const u16*)x, (const u16*)wq, ws, At, Bt);
  else       qgemm_body((const float*)x, (const float*)wq, ws, At, Bt);
}

// ---- sim[p,t,h,k] = q[p,t,h,:] . keys[h,k,p,:]  (batched 128t x 128k x 128kd GEMM) ----
template<typename T>
__device__ void sim_body(const T* keys, float* ws, float (*Qt)[33], float (*Kt)[33]){
  int tid = threadIdx.x;
  int tx = tid & 15, ty = tid >> 4;
  int tt = blockIdx.x;
  int y = blockIdx.y;
  int kh = y & 1, p = (y >> 1) & 1, h = y >> 2;
  int t0 = tt*128;
  const float* qm = ws + WS_Q;
  float* sim = ws + WS_SIM;
  int qc0 = p*1024 + h*128;
  float acc[8][8] = {};
  for (int kc = 0; kc < 4; ++kc){
    int kd0 = kc*32;
    __syncthreads();
    { int m = tid >> 1, kb = (tid & 1)*16;
      size_t base = (size_t)(t0 + m)*QC + qc0 + kd0 + kb;
      #pragma unroll
      for (int i = 0; i < 16; ++i) Qt[m][kb+i] = qm[base + i];
    }
    { int kk = tid >> 1, kb = (tid & 1)*16;
      size_t base = ((size_t)(h*NKEY + kh*128 + kk)*2 + p)*KDD + kd0 + kb;
      #pragma unroll
      for (int i = 0; i < 16; ++i) Kt[kk][kb+i] = LD1(keys, base + i);
    }
    __syncthreads();
    #pragma unroll 4
    for (int kd = 0; kd < 32; ++kd){
      float a[8], b[8];
      #pragma unroll
      for (int i = 0; i < 8; ++i) a[i] = Qt[ty*8+i][kd];
      #pragma unroll
      for (int j = 0; j < 8; ++j) b[j] = Kt[tx*8+j][kd];
      #pragma unroll
      for (int i = 0; i < 8; ++i)
        #pragma unroll
        for (int j = 0; j < 8; ++j) acc[i][j] += a[i]*b[j];
    }
  }
  for (int i = 0; i < 8; ++i){
    size_t row = (((size_t)p*TOK + t0 + ty*8 + i)*NH + h)*NKEY + kh*128 + tx*8;
    #pragma unroll
    for (int j = 0; j < 8; ++j) sim[row + j] = acc[i][j];
  }
}
__global__ __launch_bounds__(256) void k_sim(const void* keys, const int* flag, float* ws){
  __shared__ float Qt[128][33];
  __shared__ float Kt[128][33];
  if (*flag) sim_body((const u16*)keys, ws, Qt, Kt);
  else       sim_body((const float*)keys, ws, Qt, Kt);
}

// ---- top-16 insertion (sorted desc, stable: earlier candidate wins ties) ----
__device__ __forceinline__ void topk_insert(float (&bs)[16], int (&bi)[16], float v, int ind){
  int rank = 0;
  #pragma unroll
  for (int r = 0; r < 16; ++r) rank += (bs[r] >= v) ? 1 : 0;
  #pragma unroll
  for (int r = 15; r > 0; --r){ if (r > rank){ bs[r] = bs[r-1]; bi[r] = bi[r-1]; } }
  #pragma unroll
  for (int r = 0; r < 16; ++r){ if (r == rank){ bs[r] = v; bi[r] = ind; } }
}

// ---- stage-1 top-k: one thread per (p,t,h), scan 256 sims ----
__global__ __launch_bounds__(256) void k_top1(float* ws){
  int g = blockIdx.x*256 + threadIdx.x;   // 32768 = 2*T*H, g = (p*T+t)*H+h
  const float* sim = ws + WS_SIM + (size_t)g*NKEY;
  float bs[16]; int bi[16];
  #pragma unroll
  for (int r = 0; r < 16; ++r){ bs[r] = -3e38f; bi[r] = 0; }
  for (int k = 0; k < NKEY; ++k){
    float v = sim[k];
    if (v > bs[15]) topk_insert(bs, bi, v, k);
  }
  float* s1s = ws + WS_S1S;
  int* s1i = (int*)(ws + WS_S1I);
  #pragma unroll
  for (int r = 0; r < 16; ++r){ s1s[(size_t)g*16 + r] = bs[r]; s1i[(size_t)g*16 + r] = bi[r]; }
}

// ---- stage-2: cartesian merge + top-k; one thread per (t,h) ----
__global__ __launch_bounds__(256) void k_top2(float* ws){
  int g = blockIdx.x*256 + threadIdx.x;   // 16384 = T*H, g = t*H+h
  const float* sx = ws + WS_S1S + (size_t)g*16;
  const float* sy = sx + (size_t)TOK*NH*16;
  const int* ix = (const int*)(ws + WS_S1I) + (size_t)g*16;
  const int* iy = ix + (size_t)TOK*NH*16;
  float bs[16]; int bi[16];
  #pragma unroll
  for (int r = 0; r < 16; ++r){ bs[r] = -3e38f; bi[r] = 0; }
  for (int i = 0; i < 16; ++i){
    float sxi = sx[i]; int ib = ix[i]*NKEY;
    for (int j = 0; j < 16; ++j){
      float v = sxi + sy[j];
      if (v > bs[15]) topk_insert(bs, bi, v, ib + iy[j]);
    }
  }
  float* gate = ws + WS_GATE;
  int* eidx = (int*)(ws + WS_EIDX);
  #pragma unroll
  for (int r = 0; r < 16; ++r){
    gate[(size_t)g*16 + r] = 1.0f / (1.0f + expf(-bs[r]));
    eidx[(size_t)g*16 + r] = bi[r];
  }
}

// ---- expert gather: one block per token ----
template<typename T>
__device__ void expert_body(const T* x, const T* dw, const T* uw, T* out, float* ws,
                            float* xs, float* acts, int* eix){
  int tid = threadIdx.x;
  int t = blockIdx.x;
  const float* gate = ws + WS_GATE + (size_t)t*128;
  const int* eidx = (const int*)(ws + WS_EIDX) + (size_t)t*128;
  #pragma unroll
  for (int c = 0; c < 4; ++c) xs[c*256 + tid] = LD1(x, (size_t)t*DIM + c*256 + tid);
  if (tid < 128) eix[tid] = eidx[tid];
  __syncthreads();
  // phase A: h_dot per expert, wave-parallel
  int w = tid >> 6, l = tid & 63;
  const float2* xs2 = reinterpret_cast<const float2*>(xs);
  for (int eo = 0; eo < 32; ++eo){
    int e = w*32 + eo;
    size_t base = (size_t)eix[e]*DIM;
    float acc = 0.f;
    #pragma unroll
    for (int i = 0; i < 8; ++i){
      int d = i*128 + l*2;
      float2 v = LD2(dw, base + d);
      float2 xv = xs2[i*64 + l];
      acc += v.x*xv.x + v.y*xv.y;
    }
    #pragma unroll
    for (int off = 32; off >= 1; off >>= 1) acc += __shfl_down(acc, off, 64);
    if (l == 0){
      float hh = acc;
      float ge = 0.5f*hh*(1.0f + erff(hh*0.70710678118654752f)); // exact gelu
      acts[e] = gate[e]*ge;
    }
  }
  __syncthreads();
  // phase B: out[d] = sum_e acts[e]*up_w[idx[e]][d]; thread owns d = {tid*2, tid*2+1, +512...}
  float a0x=0.f, a0y=0.f, a1x=0.f, a1y=0.f;
  for (int e = 0; e < 128; ++e){
    float wv = acts[e];
    size_t base = (size_t)eix[e]*DIM;
    float2 u0 = LD2(uw, base + tid*2);
    float2 u1 = LD2(uw, base + 512 + tid*2);
    a0x += wv*u0.x; a0y += wv*u0.y;
    a1x += wv*u1.x; a1y += wv*u1.y;
  }
  size_t ob = (size_t)t*DIM;
  ST2(out, ob + tid*2, a0x, a0y);
  ST2(out, ob + 512 + tid*2, a1x, a1y);
}
__global__ __launch_bounds__(256) void k_expert(const void* x, const void* dw, const void* uw,
                                                void* out, const int* flag, float* ws){
  __shared__ float xs[DIM];
  __shared__ float acts[128];
  __shared__ int eix[128];
  if (*flag) expert_body((const u16*)x, (const u16*)dw, (const u16*)uw, (u16*)out, ws, xs, acts, eix);
  else       expert_body((const float*)x, (const float*)dw, (const float*)uw, (float*)out, ws, xs, acts, eix);
}

extern "C" void kernel_launch(void* const* d_in, const int* in_sizes, int n_in,
                              void* d_out, int out_size, void* d_ws, size_t ws_size,
                              hipStream_t stream){
  (void)in_sizes; (void)n_in; (void)out_size; (void)ws_size;
  float* ws = (float*)d_ws;
  const int* flag = (const int*)d_ws;
  const void* x     = d_in[0];
  const void* gamma = d_in[1];
  const void* beta  = d_in[2];
  const void* wq    = d_in[3];
  const void* keys  = d_in[4];
  const void* dw    = d_in[5];
  const void* uw    = d_in[6];

  k_detect<<<dim3(1), dim3(1), 0, stream>>>((const u32*)gamma, (int*)d_ws);
  k_bn_part<<<dim3(64), dim3(256), 0, stream>>>(x, flag, ws);
  k_bn_final<<<dim3(4), dim3(256), 0, stream>>>(gamma, beta, flag, ws);
  k_qgemm<<<dim3(16,16), dim3(256), 0, stream>>>(x, wq, flag, ws);
  k_sim<<<dim3(16,32), dim3(256), 0, stream>>>(keys, flag, ws);
  k_top1<<<dim3(128), dim3(256), 0, stream>>>(ws);
  k_top2<<<dim3(64), dim3(256), 0, stream>>>(ws);
  k_expert<<<dim3(2048), dim3(256), 0, stream>>>(x, dw, uw, d_out, flag, ws);
}